// Round 11
// baseline (138.317 us; speedup 1.0000x reference)
//
#include <hip/hip_runtime.h>
#include <hip/hip_bf16.h>

typedef short short8 __attribute__((ext_vector_type(8)));
typedef float floatx4 __attribute__((ext_vector_type(4)));
typedef unsigned short ushort_t;
typedef unsigned int uint32;

#define H 320
#define W 320
#define HW (H * W)
#define CG 16
#define NCH 64
#define SW 80        // strip width per wave

__device__ __forceinline__ ushort_t f2bf(float f) {
  unsigned u = __float_as_uint(f);
  return (ushort_t)((u + 0x7FFFu + ((u >> 16) & 1u)) >> 16);  // RNE (weights only)
}

// ONE WAVE per workgroup; NO barriers anywhere. Wave owns a ring-4 LDS strip
// [slot][col WH][16 ic] bf16 (32B/col -> aligned ds_read_b128 / ds_write_b128).
// Task = one output row y = k*DIL + r; walk k: stage 1 new row per task.
template<int G, int KC>
__device__ __forceinline__ void conv_wave(
    const float* __restrict__ x, const float* __restrict__ wgt,
    const float* __restrict__ bias, float* __restrict__ out,
    ushort_t* lds, int idx) {
  constexpr int DIL  = (G == 0) ? 1 : (G == 1) ? 6 : (G == 2) ? 12 : 18;
  constexpr int WH   = SW + 2 * DIL;              // 82/92/104/116
  constexpr int KMAX = (H + DIL - 1) / DIL;       // 320/54/27/18
  constexpr int NC   = (KMAX + KC - 1) / KC;

  const int lane = threadIdx.x;                   // 64 threads = 1 wave

  // decode: idx = (((b*4 + s)*NC + c)*DIL + r)   (r innermost: L2 row locality)
  const int r  = idx % DIL;
  const int t1 = idx / DIL;
  const int c  = t1 % NC;
  const int t2 = t1 / NC;
  const int s  = t2 & 3;
  const int b  = t2 >> 2;

  const int x0 = s * SW;
  const int k0 = c * KC;
  const int kcap = (H - r + DIL - 1) / DIL;       // tasks with y < H
  const int kend = (k0 + KC < kcap) ? k0 + KC : kcap;
  if (k0 >= kend) return;

  // ---- per-wave A-fragments (gathered from global; amortized over KC tasks) ----
  const int pxl = lane & 15, z = lane >> 4, icq = z & 1, zh = z >> 1;
  short8 aw[5];
#pragma unroll
  for (int t = 0; t < 5; ++t) {
    const int tp = 2 * t + zh;                    // tap = 2t + (z>>1); k-octet map
#pragma unroll
    for (int jj = 0; jj < 8; ++jj) {
      float v = 0.f;
      if (tp < 9) v = wgt[((size_t)(G * CG + pxl) * CG + icq * 8 + jj) * 9 + tp];
      aw[t][jj] = (short)f2bf(v);
    }
  }
  float bv[4];
#pragma unroll
  for (int rg = 0; rg < 4; ++rg) bv[rg] = bias[G * CG + z * 4 + rg];

  // ---- staging constants: pass p covers col lane + 64p ----
  const float* chb = x + (size_t)(b * NCH + G * CG) * HW;
  bool zm[2]; int gofs[2];
#pragma unroll
  for (int p = 0; p < 2; ++p) {
    const int cr = lane + 64 * p;
    const int cc = cr < WH ? cr : WH - 1;         // clamp: load always executes
    const int gc = x0 + cc - DIL;
    zm[p] = (cr < WH) & (gc >= 0) & (gc < W);
    gofs[p] = gc < 0 ? 0 : (gc >= W ? W - 1 : gc);
  }

  float pay[2][16];                               // statically indexed payload
  auto LOADR = [&](int rho) {
    const int yy = rho * DIL + r;
    const int yyc = yy < 0 ? 0 : (yy >= H ? H - 1 : yy);
    const float* rp = chb + (size_t)yyc * W;
#pragma unroll
    for (int p = 0; p < 2; ++p)
#pragma unroll
      for (int ch = 0; ch < 16; ++ch)
        pay[p][ch] = rp[(size_t)ch * HW + gofs[p]];  // 256B coalesced per inst
  };
  auto CVTW = [&](int rho) {
    const int yy = rho * DIL + r;
    const bool rv = (yy >= 0) & (yy < H);
    ushort_t* slotp = lds + (size_t)(rho & 3) * (WH * 16);
#pragma unroll
    for (int p = 0; p < 2; ++p) {
      const int cc = lane + 64 * p;
      const bool m = rv & zm[p];
      uint32 pk[8];
#pragma unroll
      for (int j = 0; j < 8; ++j) {
        __hip_bfloat162 h = __float22bfloat162_rn(make_float2(pay[p][2*j], pay[p][2*j+1]));
        pk[j] = m ? *(const uint32*)&h : 0u;
      }
      if (cc < WH) {                              // 2x ds_write_b128, 16B aligned
        uint32* dst = (uint32*)(slotp + (size_t)cc * 16);
        *(float4*)(dst)     = *(const float4*)(&pk[0]);
        *(float4*)(dst + 4) = *(const float4*)(&pk[4]);
      }
    }
  };
  auto COMPUTE = [&](int k) {
    const int y = k * DIL + r;
    float* outb = out + (size_t)(b * NCH + G * CG) * HW + (size_t)y * W + x0;
    const ushort_t* rowp[5];
#pragma unroll
    for (int t = 0; t < 5; ++t) {
      const int tp = 2 * t + zh;
      const int ky = tp < 9 ? tp / 3 : 0;
      const int kx = tp < 9 ? tp - ky * 3 : 0;
      rowp[t] = lds + (size_t)((k - 1 + ky) & 3) * (WH * 16)
                    + (size_t)(pxl + kx * DIL) * 16 + icq * 8;
    }
#pragma unroll
    for (int ti = 0; ti < SW / 16; ++ti) {        // 5 tiles of 16 px
      floatx4 acc = {0.f, 0.f, 0.f, 0.f};
#pragma unroll
      for (int t = 0; t < 5; ++t) {
        const short8 bf = *(const short8*)(rowp[t] + ti * 256);  // ds_read_b128
        acc = __builtin_amdgcn_mfma_f32_16x16x32_bf16(aw[t], bf, acc, 0, 0, 0);
      }
#pragma unroll
      for (int rg = 0; rg < 4; ++rg)              // C/D: col=lane&15, row=4z+rg
        outb[(size_t)(z * 4 + rg) * HW + ti * 16 + pxl] = acc[rg] + bv[rg];
    }
  };

  // ---- prologue: stage rows k0-1, k0, k0+1 (within-wave: lgkm only) ----
  LOADR(k0 - 1); CVTW(k0 - 1);
  LOADR(k0);     CVTW(k0);
  LOADR(k0 + 1); CVTW(k0 + 1);
  asm volatile("s_waitcnt lgkmcnt(0)" ::: "memory");

  // ---- task loop: free-running wave, no barriers ----
#pragma unroll 1
  for (int k = k0; k < kend; ++k) {
    if (k + 1 < kend) {                           // wave-uniform branch
      LOADR(k + 2);                               // prefetch next row
      COMPUTE(k);
      CVTW(k + 2);
      asm volatile("s_waitcnt lgkmcnt(0)" ::: "memory");  // write->read ordering
    } else {
      COMPUTE(k);
    }
  }
}

extern "C" __global__ void __launch_bounds__(64) conv_all(
    const float* __restrict__ x, const float* __restrict__ wgt,
    const float* __restrict__ bias, float* __restrict__ out) {
  extern __shared__ ushort_t lds[];
  const int bid = blockIdx.x;
  // blocks: G0 1280 (KC=8,NC=40) | G1 1728 (KC=6,NC=9) | G2 2304 (KC=5,NC=6) | G3 2304 (KC=5,NC=4)
  if (bid < 1280)      conv_wave<0, 8>(x, wgt, bias, out, lds, bid);
  else if (bid < 3008) conv_wave<1, 6>(x, wgt, bias, out, lds, bid - 1280);
  else if (bid < 5312) conv_wave<2, 5>(x, wgt, bias, out, lds, bid - 3008);
  else                 conv_wave<3, 5>(x, wgt, bias, out, lds, bid - 5312);
}

extern "C" void kernel_launch(void* const* d_in, const int* in_sizes, int n_in,
                              void* d_out, int out_size, void* d_ws, size_t ws_size,
                              hipStream_t stream) {
  const float* x    = (const float*)d_in[0];
  const float* wgt  = (const float*)d_in[1];
  const float* bias = (const float*)d_in[2];
  float* out        = (float*)d_out;

  // LDS per 1-wave block = ring-4 * WH(max 116) * 32B = 14848 B -> 11 blocks/CU
  const size_t lds_bytes = (size_t)4 * 116 * 16 * sizeof(ushort_t);
  conv_all<<<dim3(7616), dim3(64), lds_bytes, stream>>>(x, wgt, bias, out);
}

// Round 13
// 102.812 us; speedup vs baseline: 1.3453x; 1.3453x over previous
//
#include <hip/hip_runtime.h>
#include <hip/hip_bf16.h>

typedef short short8 __attribute__((ext_vector_type(8)));
typedef short short4_t __attribute__((ext_vector_type(4)));
typedef float floatx4 __attribute__((ext_vector_type(4)));
typedef unsigned short ushort_t;
typedef unsigned int uint32;

#define H 320
#define W 320
#define CG 16
#define NCH 64
#define HW (H * W)
#define CGP 20       // ushorts per LDS col (40B): conflict-free frag reads (measured 0)
#define HALFW 160

__device__ __forceinline__ ushort_t f2bf(float f) {
  unsigned u = __float_as_uint(f);
  return (ushort_t)((u + 0x7FFFu + ((u >> 16) & 1u)) >> 16);  // RNE (weights only)
}

// LDS-only barrier: does NOT drain vmcnt -> global loads/stores stay in flight.
__device__ __forceinline__ void barrier_lgkm() {
  asm volatile("s_waitcnt lgkmcnt(0)" ::: "memory");
  __builtin_amdgcn_s_barrier();
}

// Block: 256 thr = 4 waves; ring-6 LDS row buffer; straight-line task loop.
// SWAPPED MFMA: mfma(A=x_frag, B=w_frag) -> C/D has col(lane&15)=oc and
// row(4z+reg)=px, so acc is a float4 of 4 CONSECUTIVE pixels of one oc:
// epilogue = one global_store_dwordx4 per tile (was 4 scattered dwords).
template<int G>
__device__ __forceinline__ void conv_group(
    const float* __restrict__ x, const float* __restrict__ wgt,
    const float* __restrict__ bias, float* __restrict__ out,
    ushort_t* lds, int bx) {
  constexpr int DIL   = (G == 0) ? 1 : (G == 1) ? 6 : (G == 2) ? 12 : 18;
  constexpr int KOFF  = DIL & 1;
  constexpr int SHIFT = DIL + KOFF;              // lds col c <-> global col wb + c - SHIFT
  constexpr int WH    = (HALFW + 2 * DIL + KOFF + 1) & ~1;  // 164/172/184/196
  constexpr int NP    = (WH + 63) / 64;          // 3/3/3/4
  constexpr int WKS   = 16 * DIL;                // walks = DIL * 2(wb) * 8(b)
  constexpr int RPW   = (H + DIL - 1) / DIL;
  constexpr int Q     = (RPW + 3) / 4;           // 80/14/7/5 tasks per walk
  constexpr int CPW   = (G == 0) ? 12 : (G == 1) ? 2 : 1;
  constexpr int L     = (Q + CPW - 1) / CPW;     // 7/7/7/5 tasks per chunk

  const int tid = threadIdx.x;
  ushort_t* tile = lds;                          // [6][WH][CGP]
  ushort_t* swt  = lds + 6 * WH * CGP;           // [5][4][16][8] A-frag table
  uint32* swt32  = (uint32*)swt;

  // ---- weight fragment table (once per block) ----
#pragma unroll
  for (int k = 0; k < 5; ++k) {
    const int s = tid + k * 256;
    const int jp = s & 3, oc = (s >> 2) & 15, zz = (s >> 6) & 3, t = s >> 8;
    const int tp = 2 * t + (zz >> 1);
    uint32 pk = 0;
    if (tp < 9) {
      const float* wp = wgt + ((size_t)(G * CG + oc) * CG + (zz & 1) * 8 + 2 * jp) * 9 + tp;
      pk = (uint32)f2bf(wp[0]) | ((uint32)f2bf(wp[9]) << 16);
    }
    swt32[s] = pk;
  }
  __syncthreads();

  const int lane = tid & 63;
  const int wv   = tid >> 6;
  const int z = lane >> 4, icq = z & 1, pxl = lane & 15;
  short8 aw[5];
#pragma unroll
  for (int t = 0; t < 5; ++t) aw[t] = *(const short8*)&swt[((t * 4 + z) * 16 + pxl) * 8];
  const float bb = bias[G * CG + pxl];           // oc = lane&15 in swapped layout

  // ---- decode block -> (walk, chunk) ----
  const int walk  = bx % WKS;
  const int chunk = bx / WKS;
  const int r  = walk % DIL;
  const int wb = ((walk / DIL) & 1) * HALFW;
  const int b  = walk / (2 * DIL);
  const int q0 = chunk * L;
  const int qend = (q0 + L < Q) ? q0 + L : Q;

  // ---- staging constants: thread = (col = lane, ch-quad = wv) ----
  bool zm[NP]; bool inb[NP]; int gofs[NP];
#pragma unroll
  for (int p = 0; p < NP; ++p) {
    const int c = 64 * p + lane;
    inb[p] = (c < WH);
    const int gc = wb + c - SHIFT;
    zm[p] = inb[p] & (gc >= 0) & (gc < W);
    gofs[p] = gc < 0 ? 0 : (gc >= W ? W - 1 : gc);
  }
  const float* chb = x + (size_t)(b * NCH + G * CG + 4 * wv) * HW;

  auto LOADR = [&](int rho, float (&rg)[NP][4]) {
    const int yy = rho * DIL + r;
    const int yyc = yy < 0 ? 0 : (yy >= H ? H - 1 : yy);
    const float* rp = chb + (size_t)yyc * W;
#pragma unroll
    for (int p = 0; p < NP; ++p)
#pragma unroll
      for (int k = 0; k < 4; ++k)
        rg[p][k] = rp[(size_t)k * HW + gofs[p]];   // 256B coalesced per inst
  };

  auto CVTR = [&](int rho, int slot, float (&rg)[NP][4]) {
    const int yy = rho * DIL + r;
    const bool rv = (yy >= 0) & (yy < H);
#pragma unroll
    for (int p = 0; p < NP; ++p) {
      const bool m = rv & zm[p];
      const __hip_bfloat162 h01 = __float22bfloat162_rn(make_float2(rg[p][0], rg[p][1]));
      const __hip_bfloat162 h23 = __float22bfloat162_rn(make_float2(rg[p][2], rg[p][3]));
      uint2 pk;
      pk.x = m ? *(const uint32*)&h01 : 0u;
      pk.y = m ? *(const uint32*)&h23 : 0u;
      if (inb[p]) {
        const int c = 64 * p + lane;
        *(uint2*)&tile[(size_t)(slot * WH + c) * CGP + wv * 4] = pk;  // ds_write_b64
      }
    }
  };

  auto COMPUTE = [&](int q, int m6) {
    const int y = (4 * q + wv) * DIL + r;
    if (y >= H) return;
    const int zh = z >> 1;
    // swapped C/D: lane&15 = oc, regs = px {4z..4z+3}
    float* outb = out + (size_t)(b * NCH + G * CG + pxl) * HW + (size_t)y * W + wb + 4 * z;
    const ushort_t* rowp[5];                 // statically indexed (unrolled t)
#pragma unroll
    for (int t = 0; t < 5; ++t) {
      const int tp = 2 * t + zh;
      const int ky = tp < 9 ? tp / 3 : 0;
      const int kx = tp < 9 ? tp - ky * 3 : 0;
      int s = m6 + wv + ky; s -= (s >= 6) ? 6 : 0;   // slot of row j = wv+ky
      rowp[t] = tile + (size_t)s * (WH * CGP) + (size_t)(pxl + kx * DIL + KOFF) * CGP + icq * 8;
    }
#pragma unroll 2
    for (int ti = 0; ti < HALFW / 16; ++ti) {
      floatx4 acc = {0.f, 0.f, 0.f, 0.f};
#pragma unroll
      for (int t = 0; t < 5; ++t) {
        const ushort_t* pf = rowp[t] + ti * 16 * CGP;
        const short4_t lo = *(const short4_t*)pf;
        const short4_t hi = *(const short4_t*)(pf + 4);
        const short8 bf = {lo[0], lo[1], lo[2], lo[3], hi[0], hi[1], hi[2], hi[3]};
        acc = __builtin_amdgcn_mfma_f32_16x16x32_bf16(bf, aw[t], acc, 0, 0, 0);  // A=x, B=w
      }
      floatx4 st = {acc[0] + bb, acc[1] + bb, acc[2] + bb, acc[3] + bb};
      __builtin_nontemporal_store(st, (floatx4*)(outb + ti * 16));  // 1KB/inst
    }
  };

  auto wrap6 = [](int v) { return v >= 6 ? v - 6 : v; };
  int m6 = (4 * q0 + 5) % 6;                 // slot of row rho = 4q-1 (ring-6)

  // ---- prologue: stage 6 rows ----
  {
    float ra[NP][4], rb[NP][4];
    LOADR(4 * q0 - 1, ra); LOADR(4 * q0 + 0, rb);
    CVTR(4 * q0 - 1, wrap6(m6 + 0), ra); CVTR(4 * q0 + 0, wrap6(m6 + 1), rb);
    LOADR(4 * q0 + 1, ra); LOADR(4 * q0 + 2, rb);
    CVTR(4 * q0 + 1, wrap6(m6 + 2), ra); CVTR(4 * q0 + 2, wrap6(m6 + 3), rb);
    LOADR(4 * q0 + 3, ra); LOADR(4 * q0 + 4, rb);
    CVTR(4 * q0 + 3, wrap6(m6 + 4), ra); CVTR(4 * q0 + 4, wrap6(m6 + 5), rb);
  }
  barrier_lgkm();

  // ---- task loop: straight-line body; final iteration peeled ----
#pragma unroll 1
  for (int q = q0; q < qend - 1; ++q) {
    float ra[NP][4], rb[NP][4], rc[NP][4], rd[NP][4];
    LOADR(4 * q + 5, ra); LOADR(4 * q + 6, rb);
    LOADR(4 * q + 7, rc); LOADR(4 * q + 8, rd);
    COMPUTE(q, m6);                          // prefetch drains under this
    barrier_lgkm();                          // tile readers done (lgkm only)
    CVTR(4 * q + 5, m6,            ra);
    CVTR(4 * q + 6, wrap6(m6 + 1), rb);
    CVTR(4 * q + 7, wrap6(m6 + 2), rc);
    CVTR(4 * q + 8, wrap6(m6 + 3), rd);
    barrier_lgkm();                          // tile ready for next task
    m6 = wrap6(m6 + 4);
  }
  COMPUTE(qend - 1, m6);                     // epilogue: no staging
}

extern "C" __global__ void __launch_bounds__(256, 3) conv_all(
    const float* __restrict__ x, const float* __restrict__ wgt,
    const float* __restrict__ bias, float* __restrict__ out) {
  extern __shared__ ushort_t lds[];
  const int bid = blockIdx.x;
  if (bid < 288)      conv_group<3>(x, wgt, bias, out, lds, bid);        // 288 blocks
  else if (bid < 480) conv_group<2>(x, wgt, bias, out, lds, bid - 288);  // 192
  else if (bid < 672) conv_group<1>(x, wgt, bias, out, lds, bid - 480);  // 192
  else                conv_group<0>(x, wgt, bias, out, lds, bid - 672);  // 192
}

extern "C" void kernel_launch(void* const* d_in, const int* in_sizes, int n_in,
                              void* d_out, int out_size, void* d_ws, size_t ws_size,
                              hipStream_t stream) {
  const float* x    = (const float*)d_in[0];
  const float* wgt  = (const float*)d_in[1];
  const float* bias = (const float*)d_in[2];
  float* out        = (float*)d_out;

  // dynamic LDS (max over groups, G3): 6*196*20*2 + 5120 = 52160 B -> 3 blocks/CU
  const size_t lds_bytes = (size_t)(6 * 196 * CGP + 5 * 4 * 16 * 8) * 2;
  conv_all<<<dim3(864), dim3(256), lds_bytes, stream>>>(x, wgt, bias, out);
}